// Round 12
// baseline (962.743 us; speedup 1.0000x reference)
//
#include <hip/hip_runtime.h>
#include <hip/hip_bf16.h>
#include <hip/hip_fp16.h>

// R12: R11 de-spilled (sequential row-a/row-b in P2, premasked consts)
// + pair-split P4 (lanes<32 own state & compute sig(i),sig(f); lanes>=32
// compute tanh(g),sig(o); shfl_xor(32) joins) -> trans chain 6->3 deep,
// all 16 waves active in P4, lower register pressure.
#define TM1 127
#define NB  2048

typedef short s16x8 __attribute__((ext_vector_type(8)));
typedef _Float16 h16x8 __attribute__((ext_vector_type(8)));
typedef _Float16 h16x2 __attribute__((ext_vector_type(2)));
typedef float f32x4 __attribute__((ext_vector_type(4)));
typedef unsigned short u16x8 __attribute__((ext_vector_type(8)));

#define K1 1.4426950408889634f   /* log2(e)   */
#define K2 2.8853900817779268f   /* 2*log2(e) */

// ---- ws layout (bytes) ----
#define WS_XWK   0ull                       /* EXW f16 [2048][16][128][8] = 67,108,864 */
#define WS_FX    67108864ull                /* [2048][128] f32 */
#define WS_GX    (WS_FX + 1048576ull)
#define WS_FRAG  (WS_GX + 1048576ull)       /* 192 tiles * 64 lanes * 16B */
#define WS_PAR   (WS_FRAG + 196608ull)      /* packed params, 5392 B */

// ---- k_main LDS layout (bytes) ----
#define L_XW    0        /* EXW [4][16][128][8] f16 = 131072 */
#define L_DCA   131072   /* [8 kt][64 lane][8] bf16 = 8192 */
#define L_EPH   139264   /* [4][128] f16 = 1024 */
#define L_GT    140288   /* [512][4] f16 = 4096 */
#define L_SP    144384   /* [16 waves][4] f32 = 256 */
#define L_Y     144640   /* [4][128] f32 = 2048 */
#define L_PAR   146688   /* 5392 -> pad 5408 */
#define L_RED   152096   /* [512] f32 = 2048 */
#define L_CTX   154144   /* [4] f32 */
#define L_TOTAL 154160

__device__ __forceinline__ float fexp2(float x){
#if __has_builtin(__builtin_amdgcn_exp2f)
  return __builtin_amdgcn_exp2f(x);
#else
  return exp2f(x);
#endif
}
__device__ __forceinline__ float frcp(float x){
#if __has_builtin(__builtin_amdgcn_rcpf)
  return __builtin_amdgcn_rcpf(x);
#else
  return 1.0f / x;
#endif
}
__device__ __forceinline__ _Float16 hrcp(_Float16 x){
#if __has_builtin(__builtin_amdgcn_rcph)
  return __builtin_amdgcn_rcph(x);
#else
  return (_Float16)frcp((float)x);
#endif
}
#if __has_builtin(__builtin_amdgcn_fdot2)
#define FDOT2(a,b,c) __builtin_amdgcn_fdot2((a),(b),(c),false)
#else
#define FDOT2(a,b,c) fmaf((float)(a)[0],(float)(b)[0], fmaf((float)(a)[1],(float)(b)[1],(c)))
#endif
__device__ __forceinline__ unsigned short f2bf(float f){
  unsigned u = __builtin_bit_cast(unsigned, f);
  u = (u + 0x7FFFu + ((u >> 16) & 1u)) >> 16;
  return (unsigned short)u;
}
__device__ __forceinline__ unsigned short f2h(float f){
  _Float16 h = (_Float16)f;
  return __builtin_bit_cast(unsigned short, h);
}
__device__ __forceinline__ float h2f(unsigned short u){
  return (float)__builtin_bit_cast(_Float16, u);
}
#if __has_builtin(__builtin_amdgcn_update_dpp)
template<int C>
__device__ __forceinline__ float dppadd(float v){
  int t = __builtin_amdgcn_update_dpp(0, __builtin_bit_cast(int, v), C, 0xF, 0xF, true);
  return v + __builtin_bit_cast(float, t);
}
#define HAVE_DPP 1
#else
#define HAVE_DPP 0
#endif

// ============ k1: EXW = 2^(clamp((X @ W1x^T)*K2)), f16 blocked [b][jblk][i][8] ============
__global__ __launch_bounds__(256) void k_xw(const float* __restrict__ X,
                                            const float* __restrict__ W1,
                                            unsigned short* __restrict__ xwk){
  extern __shared__ char smem[];
  unsigned short* A  = (unsigned short*)smem;            // [128][136] bf16 (i,k)
  unsigned short* Bt = (unsigned short*)(smem + 34816);  // [128][136] bf16 (j,k)
  const int tid = threadIdx.x;
  const int bg = blockIdx.x;
  const float* Xb = X + (size_t)bg * TM1 * 128;
  for (int idx = tid; idx < 8192; idx += 256){
    int i = idx >> 6, k2 = (idx & 63) * 2;
    float x0 = 0.f, x1 = 0.f;
    if (i < TM1){ float2 v = *(const float2*)(Xb + i*128 + k2); x0 = v.x; x1 = v.y; }
    ((unsigned*)A)[i*68 + (idx & 63)] = (unsigned)f2bf(x0) | ((unsigned)f2bf(x1) << 16);
  }
  for (int idx = tid; idx < 8192; idx += 256){
    int j = idx >> 6, k2 = (idx & 63) * 2;
    float2 v = *(const float2*)(W1 + j*384 + 256 + k2);
    ((unsigned*)Bt)[j*68 + (idx & 63)] = (unsigned)f2bf(v.x) | ((unsigned)f2bf(v.y) << 16);
  }
  __syncthreads();
  const int wv = tid >> 6, l = tid & 63;
  f32x4 acc[8][2];
#pragma unroll
  for (int mt = 0; mt < 8; ++mt)
#pragma unroll
    for (int nt = 0; nt < 2; ++nt) acc[mt][nt] = (f32x4){0.f,0.f,0.f,0.f};
#pragma unroll
  for (int kt = 0; kt < 4; ++kt){
    s16x8 bf0 = *(const s16x8*)(Bt + ((wv*2+0)*16 + (l&15))*136 + (l>>4)*8 + kt*32);
    s16x8 bf1 = *(const s16x8*)(Bt + ((wv*2+1)*16 + (l&15))*136 + (l>>4)*8 + kt*32);
#pragma unroll
    for (int mt = 0; mt < 8; ++mt){
      s16x8 af = *(const s16x8*)(A + (mt*16 + (l&15))*136 + (l>>4)*8 + kt*32);
      acc[mt][0] = __builtin_amdgcn_mfma_f32_16x16x32_bf16(af, bf0, acc[mt][0], 0,0,0);
      acc[mt][1] = __builtin_amdgcn_mfma_f32_16x16x32_bf16(af, bf1, acc[mt][1], 0,0,0);
    }
  }
  unsigned short* dst = xwk + (size_t)bg * 16384;
#pragma unroll
  for (int mt = 0; mt < 8; ++mt){
#pragma unroll
    for (int nt = 0; nt < 2; ++nt){
      int j = (wv*2+nt)*16 + (l & 15);
      int jblk = j >> 3, jr = j & 7;
#pragma unroll
      for (int r = 0; r < 4; ++r){
        int i = mt*16 + (l>>4)*4 + r;
        float ux = fminf(fmaxf(acc[mt][nt][r] * K2, -15.f), 15.f);
        dst[(jblk*128 + i)*8 + jr] = f2h(fexp2(ux));
      }
    }
  }
}

// ============ k1b: FX = X @ fcW[0:128], GX = X @ fcfW[128:256]  (f32 accurate) ============
__global__ __launch_bounds__(128) void k_fxgx(const float* __restrict__ X,
                                              const float* __restrict__ fcW,
                                              const float* __restrict__ fcfW,
                                              float* __restrict__ FX,
                                              float* __restrict__ GX){
  const int bg = blockIdx.x;
  const int l = threadIdx.x & 63, wv = threadIdx.x >> 6;
  float fw0 = fcW[l], fw1 = fcW[64 + l];
  float gw0 = fcfW[128 + l], gw1 = fcfW[192 + l];
  const float* Xb = X + (size_t)bg * TM1 * 128;
  for (int i = wv; i < TM1; i += 2){
    float x0 = Xb[i*128 + l], x1 = Xb[i*128 + 64 + l];
    float p = x0*fw0 + x1*fw1;
    float g = x0*gw0 + x1*gw1;
#pragma unroll
    for (int m = 1; m < 64; m <<= 1){ p += __shfl_xor(p, m, 64); g += __shfl_xor(g, m, 64); }
    if (l == 0){ FX[bg*128 + i] = p; GX[bg*128 + i] = g; }
  }
  if (threadIdx.x == 0){ FX[bg*128 + 127] = 0.f; GX[bg*128 + 127] = 0.f; }
}

// ============ k2: weight B-fragment blob + params pack ============
__global__ __launch_bounds__(64) void k_pack(const float* __restrict__ W1,
                                             const float* __restrict__ Whh,
                                             const float* __restrict__ W2,
                                             const float* __restrict__ b1,
                                             const float* __restrict__ bih,
                                             const float* __restrict__ bhh,
                                             const float* __restrict__ Wih,
                                             const float* __restrict__ fcW,
                                             const float* __restrict__ fcb,
                                             const float* __restrict__ fcfW,
                                             const float* __restrict__ fcfb,
                                             char* __restrict__ ws){
  const int tile = blockIdx.x, l = threadIdx.x;
  s16x8 v;
  if (tile < 64){
    int nt = tile >> 3, ct = tile & 7;
    int row = nt*16 + (l & 15);
    int kb = ct*32 + (l >> 4)*8;
#pragma unroll
    for (int r = 0; r < 8; ++r) v[r] = (short)f2bf(W1[row*384 + kb + r]);
  } else {
    int g = tile - 64; int nt = g >> 2, kt = g & 3;
    int row = nt*16 + (l & 15);
    int kb = kt*32 + (l >> 4)*8;
#pragma unroll
    for (int r = 0; r < 8; ++r) v[r] = (short)f2bf(Whh[row*128 + kb + r]);
  }
  *(s16x8*)(ws + WS_FRAG + ((size_t)tile*64 + l)*16) = v;
  if (tile == 0){
    char* par = ws + WS_PAR;
    for (int j = l; j < 128; j += 64){
      ((unsigned short*)par)[j] = f2h(-2.f * W2[j]);   // w2h f16
      ((float*)(par + 256))[j] = b1[j] * K2;           // b1K
      ((float*)(par + 4864))[j] = fcfW[j];             // fcf_d
    }
    for (int n = l; n < 512; n += 64){
      ((float*)(par + 768))[n] = bih[n] + bhh[n];      // biassum
      ((float*)(par + 2816))[n] = Wih[n];              // W_ih
    }
    if (l == 0){
      ((float*)(par + 5376))[0] = fcW[128];            // y coeff
      ((float*)(par + 5376))[1] = fcb[0];
      ((float*)(par + 5376))[2] = fcfb[0];
      ((float*)(par + 5376))[3] = 0.f;
    }
  }
}

// ============ k3: persistent recurrence, 4 batches / block ============
__global__ __launch_bounds__(1024, 4) void k_main(const char* __restrict__ ws,
                                                  const float* __restrict__ dn,
                                                  const float* __restrict__ cn,
                                                  const float* __restrict__ yprev,
                                                  float* __restrict__ out){
  extern __shared__ char smem[];
  const int tid = threadIdx.x;
  const int wv = tid >> 6, l = tid & 63;
  const int bg0 = blockIdx.x * 4;
  const bool wlt8 = (wv < 8);

  // ---- P0: stage EXW tile, yprev, params; zero dcA ----
  {
    const u16x8* src = (const u16x8*)(ws + (size_t)bg0 * 32768);
    u16x8* dstv = (u16x8*)(smem + L_XW);
    for (int c = tid; c < 8192; c += 1024) dstv[c] = src[c];
    const f32x4* ps = (const f32x4*)(ws + WS_PAR);
    f32x4* pd = (f32x4*)(smem + L_PAR);
    for (int c = tid; c < 337; c += 1024) pd[c] = ps[c];
    float* yd = (float*)(smem + L_Y);
    if (tid < 512){
      int b = tid >> 7, tt = tid & 127;
      yd[tid] = (tt < TM1) ? yprev[(size_t)(bg0 + b)*TM1 + tt] : 0.f;
    }
    unsigned* z = (unsigned*)(smem + L_DCA);
    for (int c = tid; c < 2048; c += 1024) z[c] = 0u;
  }

  // weight fragments (persistent in VGPRs/AGPRs): 3 groups x 4 k-tiles per wave
  size_t t0, t1, t2;
  if (wlt8){ t0 = (size_t)wv * 8192; t1 = t0 + 4096; t2 = 65536 + (size_t)wv * 4096; }
  else { int m = wv - 8; t0 = 65536 + (size_t)(8 + m*3) * 4096; t1 = t0 + 4096; t2 = t1 + 4096; }
  const char* blob = ws + WS_FRAG;
#define LB(o) (*(const s16x8*)(blob + (o) + (size_t)l*16))
  s16x8 w00=LB(t0), w01=LB(t0+1024), w02=LB(t0+2048), w03=LB(t0+3072);
  s16x8 w10=LB(t1), w11=LB(t1+1024), w12=LB(t1+2048), w13=LB(t1+3072);
  s16x8 w20=LB(t2), w21=LB(t2+1024), w22=LB(t2+2048), w23=LB(t2+3072);
#undef LB

  // P4 pair mapping: owners = lanes 0..31 of each wave; partner at l+32
  const int slot = wv*32 + (l & 31);
  const int pb = slot & 3, pj = (slot >> 2) & 127;
  const bool owner = (l < 32);
  const int ga = owner ? 0 : 2;     // owner: gates i,f ; partner: gates g,o
  float d_reg = 0.f, c_reg = 0.f;
  if (owner){ d_reg = dn[(bg0+pb)*128 + pj]; c_reg = cn[(bg0+pb)*128 + pj]; }

  // P2 mapping: wave -> (batch b2, 32-row block r0); lane -> (row pair q, slice s2)
  const int b2 = wv >> 2, r0 = (wv & 3) * 32, q = l & 15, s2 = l >> 4;
  const int i2a = r0 + q, i2b = r0 + 16 + q;
  const float sel = (l < 16) ? 1.f : 0.f;
  const float mbv = (i2b < TM1) ? 1.f : 0.f;
  const float ma = sel;
  const float mb2 = mbv * sel;
  const float fxa2 = ((const float*)(ws + WS_FX))[(bg0 + b2)*128 + i2a] * sel;
  const float gxa2 = ((const float*)(ws + WS_GX))[(bg0 + b2)*128 + i2a] * sel;
  const float fxbm = ((const float*)(ws + WS_FX))[(bg0 + b2)*128 + i2b] * mb2;
  const float gxbm = ((const float*)(ws + WS_GX))[(bg0 + b2)*128 + i2b] * mb2;

  __syncthreads();
  unsigned short* dcA = (unsigned short*)(smem + L_DCA);
  const int wr_d = ((pj >> 5)      * 64 + ((pj >> 3) & 3) * 16 + pb) * 8 + (pj & 7);
  const int wr_c = (((pj >> 5) + 4) * 64 + ((pj >> 3) & 3) * 16 + pb) * 8 + (pj & 7);
  if (owner){ dcA[wr_d] = f2bf(d_reg); dcA[wr_c] = f2bf(c_reg); }

  unsigned short* eph = (unsigned short*)(smem + L_EPH);
  unsigned short* gt16 = (unsigned short*)(smem + L_GT);
  float* red = (float*)(smem + L_RED);
  float* ctxL = (float*)(smem + L_CTX);
  const float* yL = (const float*)(smem + L_Y);
  const float* b1K  = (const float*)(smem + L_PAR + 256);
  const float* bsum = (const float*)(smem + L_PAR + 768);
  const float* wih  = (const float*)(smem + L_PAR + 2816);
  const float* fcfd = (const float*)(smem + L_PAR + 4864);
  const float* scal = (const float*)(smem + L_PAR + 5376);

  // hoist per-thread constants (2 gates per lane)
  float wa_ = wih[ga*128 + pj],      wb_ = wih[ga*128 + 128 + pj];
  float ba_ = bsum[ga*128 + pj],     bb_ = bsum[ga*128 + 128 + pj];
  float fd_ = fcfd[pj];
  float sc0 = scal[0], sc1 = scal[1];
  __syncthreads();

  const int abyte = l * 16;
  const int cb = wlt8 ? 1 : 0;
  float ctxg = 0.f;

  // P2 loop-invariant bases (ushort units): slice s2 covers jblk = s2*4 + k
  const unsigned short* xwa = (const unsigned short*)(smem + L_XW)
                              + ((b2*16 + s2*4)*128 + i2a)*8;
  const unsigned short* epb0 = eph + b2*128 + s2*32;
  const unsigned short* w2b = (const unsigned short*)(smem + L_PAR) + s2*32;

  for (int t = 0; t < TM1; ++t){
    // ---- P1: MFMA pre (K=256 over [d;c]) + gates_hh (K=128 over d); EP = 2^pre ----
    {
      f32x4 z = (f32x4){0.f,0.f,0.f,0.f};
      f32x4 ac0 = z, ac1 = z, ac2 = z;
      s16x8 a0, a1, a2, a3, b0, b1, b2r, b3;
      a0 = *(const s16x8*)((char*)dcA + 0*1024 + abyte);
      a1 = *(const s16x8*)((char*)dcA + 1*1024 + abyte);
      a2 = *(const s16x8*)((char*)dcA + 2*1024 + abyte);
      a3 = *(const s16x8*)((char*)dcA + 3*1024 + abyte);
      if (cb){
        b0 = *(const s16x8*)((char*)dcA + 4*1024 + abyte);
        b1 = *(const s16x8*)((char*)dcA + 5*1024 + abyte);
        b2r = *(const s16x8*)((char*)dcA + 6*1024 + abyte);
        b3 = *(const s16x8*)((char*)dcA + 7*1024 + abyte);
      } else { b0 = a0; b1 = a1; b2r = a2; b3 = a3; }
      ac0 = __builtin_amdgcn_mfma_f32_16x16x32_bf16(a0, w00, ac0, 0,0,0);
      ac0 = __builtin_amdgcn_mfma_f32_16x16x32_bf16(a1, w01, ac0, 0,0,0);
      ac0 = __builtin_amdgcn_mfma_f32_16x16x32_bf16(a2, w02, ac0, 0,0,0);
      ac0 = __builtin_amdgcn_mfma_f32_16x16x32_bf16(a3, w03, ac0, 0,0,0);
      ac2 = __builtin_amdgcn_mfma_f32_16x16x32_bf16(a0, w20, ac2, 0,0,0);
      ac2 = __builtin_amdgcn_mfma_f32_16x16x32_bf16(a1, w21, ac2, 0,0,0);
      ac2 = __builtin_amdgcn_mfma_f32_16x16x32_bf16(a2, w22, ac2, 0,0,0);
      ac2 = __builtin_amdgcn_mfma_f32_16x16x32_bf16(a3, w23, ac2, 0,0,0);
      ac1 = __builtin_amdgcn_mfma_f32_16x16x32_bf16(b0, w10, ac1, 0,0,0);
      ac1 = __builtin_amdgcn_mfma_f32_16x16x32_bf16(b1, w11, ac1, 0,0,0);
      ac1 = __builtin_amdgcn_mfma_f32_16x16x32_bf16(b2r, w12, ac1, 0,0,0);
      ac1 = __builtin_amdgcn_mfma_f32_16x16x32_bf16(b3, w13, ac1, 0,0,0);
      if (l < 16){
        if (wlt8){
          int j = wv*16 + l;
          float bb = b1K[j];
          float u0 = fminf(fmaxf((ac0[0] + ac1[0])*K2 + bb, -15.f), 15.f);
          float u1 = fminf(fmaxf((ac0[1] + ac1[1])*K2 + bb, -15.f), 15.f);
          float u2 = fminf(fmaxf((ac0[2] + ac1[2])*K2 + bb, -15.f), 15.f);
          float u3 = fminf(fmaxf((ac0[3] + ac1[3])*K2 + bb, -15.f), 15.f);
          eph[0*128 + j] = f2h(fexp2(u0));
          eph[1*128 + j] = f2h(fexp2(u1));
          eph[2*128 + j] = f2h(fexp2(u2));
          eph[3*128 + j] = f2h(fexp2(u3));
          unsigned lo = (unsigned)f2h(ac2[0]) | ((unsigned)f2h(ac2[1]) << 16);
          unsigned hi = (unsigned)f2h(ac2[2]) | ((unsigned)f2h(ac2[3]) << 16);
          *(uint2*)((char*)gt16 + j*8) = make_uint2(lo, hi);
        } else {
          int nb = (8 + (wv - 8)*3)*16 + l;
          unsigned lo, hi;
          lo = (unsigned)f2h(ac0[0]) | ((unsigned)f2h(ac0[1]) << 16);
          hi = (unsigned)f2h(ac0[2]) | ((unsigned)f2h(ac0[3]) << 16);
          *(uint2*)((char*)gt16 + nb*8) = make_uint2(lo, hi);
          lo = (unsigned)f2h(ac1[0]) | ((unsigned)f2h(ac1[1]) << 16);
          hi = (unsigned)f2h(ac1[2]) | ((unsigned)f2h(ac1[3]) << 16);
          *(uint2*)((char*)gt16 + (nb+16)*8) = make_uint2(lo, hi);
          lo = (unsigned)f2h(ac2[0]) | ((unsigned)f2h(ac2[1]) << 16);
          hi = (unsigned)f2h(ac2[2]) | ((unsigned)f2h(ac2[3]) << 16);
          *(uint2*)((char*)gt16 + (nb+32)*8) = make_uint2(lo, hi);
        }
      }
    }
    __syncthreads();   // bar A

    // ---- P2 (+fused P3): 2 rows x 32 j per lane; row a then row b (low pressure) ----
    {
      float sacc_a = 0.f, sacc_b = 0.f;
#pragma unroll
      for (int k = 0; k < 4; ++k){
        h16x8 ep = *(const h16x8*)(epb0 + k*8);
        h16x8 w2 = *(const h16x8*)(w2b + k*8);
        {
          h16x8 ew = *(const h16x8*)(xwa + k*1024);
          h16x8 D = ew * ep + (_Float16)1.0f;
          h16x2 r0 = { hrcp(D[0]), hrcp(D[1]) };
          h16x2 r1 = { hrcp(D[2]), hrcp(D[3]) };
          h16x2 r2 = { hrcp(D[4]), hrcp(D[5]) };
          h16x2 r3 = { hrcp(D[6]), hrcp(D[7]) };
          sacc_a = FDOT2(r0, ((h16x2){w2[0],w2[1]}), sacc_a);
          sacc_a = FDOT2(r1, ((h16x2){w2[2],w2[3]}), sacc_a);
          sacc_a = FDOT2(r2, ((h16x2){w2[4],w2[5]}), sacc_a);
          sacc_a = FDOT2(r3, ((h16x2){w2[6],w2[7]}), sacc_a);
        }
        {
          h16x8 ew = *(const h16x8*)(xwa + k*1024 + 128);
          h16x8 D = ew * ep + (_Float16)1.0f;
          h16x2 r0 = { hrcp(D[0]), hrcp(D[1]) };
          h16x2 r1 = { hrcp(D[2]), hrcp(D[3]) };
          h16x2 r2 = { hrcp(D[4]), hrcp(D[5]) };
          h16x2 r3 = { hrcp(D[6]), hrcp(D[7]) };
          sacc_b = FDOT2(r0, ((h16x2){w2[0],w2[1]}), sacc_b);
          sacc_b = FDOT2(r1, ((h16x2){w2[2],w2[3]}), sacc_b);
          sacc_b = FDOT2(r2, ((h16x2){w2[4],w2[5]}), sacc_b);
          sacc_b = FDOT2(r3, ((h16x2){w2[6],w2[7]}), sacc_b);
        }
      }
      // combine 4 slices (lanes q, q+16, q+32, q+48) -> full row sums
      float sa = sacc_a + __shfl_xor(sacc_a, 16, 64);
      sa += __shfl_xor(sa, 32, 64);
      float sb = sacc_b + __shfl_xor(sacc_b, 16, 64);
      sb += __shfl_xor(sb, 32, 64);
      float eea = fexp2(sa * K1);
      float eeb = fexp2(sb * K1);
      float ee = eea * ma + eeb * mb2;
      float aa = eea * fxa2 + eeb * fxbm;
      float gg = eea * gxa2 + eeb * gxbm;
      // reduce over lanes 0..15 (others carry zeros)
#if HAVE_DPP
      ee = dppadd<0xB1>(ee);  aa = dppadd<0xB1>(aa);  gg = dppadd<0xB1>(gg);
      ee = dppadd<0x4E>(ee);  aa = dppadd<0x4E>(aa);  gg = dppadd<0x4E>(gg);
      ee = dppadd<0x124>(ee); aa = dppadd<0x124>(aa); gg = dppadd<0x124>(gg);
      ee = dppadd<0x128>(ee); aa = dppadd<0x128>(aa); gg = dppadd<0x128>(gg);
      if (l == 0) *(f32x4*)(smem + L_SP + wv*16) = (f32x4){ee, aa, gg, 0.f};
#else
#pragma unroll
      for (int m = 1; m < 16; m <<= 1){
        ee += __shfl_xor(ee, m, 64);
        aa += __shfl_xor(aa, m, 64);
        gg += __shfl_xor(gg, m, 64);
      }
      if (l == 0) *(f32x4*)(smem + L_SP + wv*16) = (f32x4){ee, aa, gg, 0.f};
#endif
    }
    __syncthreads();   // bar B

    // ---- P4: pair-split LSTM pointwise (all 16 waves) ----
    {
      const f32x4* sp = (const f32x4*)(smem + L_SP) + pb*4;
      f32x4 p0 = sp[0], p1 = sp[1], p2 = sp[2], p3 = sp[3];
      float E = (p0[0]+p1[0]) + (p2[0]+p3[0]);
      float A = (p0[1]+p1[1]) + (p2[1]+p3[1]);
      float G = (p0[2]+p1[2]) + (p2[2]+p3[2]);
      float rE = frcp(E);
      float yt = yL[pb*128 + t];
      float ymv = A*rE + sc0*yt + sc1;
      ctxg = G*rE;
      float xa = h2f(gt16[ga*512 + slot])       + wa_*ymv + ba_;
      float xb = h2f(gt16[ga*512 + 512 + slot]) + wb_*ymv + bb_;
      // owner: va = sigmoid(xa)=si ; partner: va = tanh(xa)=tg
      float u1 = owner ? (-xa*K1) : (xa*K2);
      float r1 = frcp(1.f + fexp2(u1));
      float va = owner ? r1 : (1.f - 2.f*r1);
      float vb = frcp(1.f + fexp2(-xb*K1));      // sf (owner) / so (partner)
      float pva = __shfl_xor(va, 32, 64);
      float pvb = __shfl_xor(vb, 32, 64);
      if (owner){
        c_reg = vb*c_reg + va*pva;               // sf*c + si*tg
        float tc = 1.f - 2.f*frcp(1.f + fexp2(c_reg*K2));
        d_reg = pvb*tc;                          // so*tanh(c)
        dcA[wr_d] = f2bf(d_reg);
        dcA[wr_c] = f2bf(c_reg);
      }
    }
    __syncthreads();   // bar C
  }

  // ---- epilogue: outputs ----
  if (owner){
    out[2048 + (bg0 + pb)*128 + pj] = d_reg;
    out[2048 + 262144 + (bg0 + pb)*128 + pj] = c_reg;
    red[pb*128 + pj] = fd_ * d_reg;
    if (pj == 0) ctxL[pb] = ctxg;
  }
  __syncthreads();
  if (wv < 4){
    float v = red[wv*128 + l] + red[wv*128 + 64 + l];
#pragma unroll
    for (int m = 1; m < 64; m <<= 1) v += __shfl_xor(v, m, 64);
    if (l == 0) out[bg0 + wv] = v + ctxL[wv] + ((const float*)(smem + L_PAR + 5376))[2];
  }
}

extern "C" void kernel_launch(void* const* d_in, const int* in_sizes, int n_in,
                              void* d_out, int out_size, void* d_ws, size_t ws_size,
                              hipStream_t stream){
  const float* X     = (const float*)d_in[0];
  const float* yprev = (const float*)d_in[1];
  const float* dn    = (const float*)d_in[2];
  const float* cn    = (const float*)d_in[3];
  const float* W1    = (const float*)d_in[4];
  const float* b1    = (const float*)d_in[5];
  const float* W2    = (const float*)d_in[6];
  /* d_in[7] = attn_b2: softmax-shift-invariant, unused */
  const float* Wih   = (const float*)d_in[8];
  const float* Whh   = (const float*)d_in[9];
  const float* bih   = (const float*)d_in[10];
  const float* bhh   = (const float*)d_in[11];
  const float* fcW   = (const float*)d_in[12];
  const float* fcb   = (const float*)d_in[13];
  const float* fcfW  = (const float*)d_in[14];
  const float* fcfb  = (const float*)d_in[15];
  char* ws = (char*)d_ws;
  float* out = (float*)d_out;
  (void)in_sizes; (void)n_in; (void)out_size; (void)ws_size;

  hipFuncSetAttribute(reinterpret_cast<const void*>(k_xw),
                      hipFuncAttributeMaxDynamicSharedMemorySize, 69632);
  hipFuncSetAttribute(reinterpret_cast<const void*>(k_main),
                      hipFuncAttributeMaxDynamicSharedMemorySize, L_TOTAL);

  k_xw<<<2048, 256, 69632, stream>>>(X, W1, (unsigned short*)ws);
  k_fxgx<<<2048, 128, 0, stream>>>(X, fcW, fcfW,
                                   (float*)(ws + WS_FX), (float*)(ws + WS_GX));
  k_pack<<<192, 64, 0, stream>>>(W1, Whh, W2, b1, bih, bhh, Wih,
                                 fcW, fcb, fcfW, fcfb, ws);
  k_main<<<512, 1024, L_TOTAL, stream>>>(ws, dn, cn, yprev, out);
}

// Round 13
// 910.827 us; speedup vs baseline: 1.0570x; 1.0570x over previous
//
#include <hip/hip_runtime.h>
#include <hip/hip_bf16.h>
#include <hip/hip_fp16.h>

// R13 = R5 verbatim (best proven: 913us, no spill, conflicts 3.1e6).
// Terminal revert after 8 variations (R6-R12) all regressed on the
// 64-arch-VGPR wall / trans-vs-VALU tradeoff / barrier structure.
#define TM1 127
#define NB  2048

typedef short s16x8 __attribute__((ext_vector_type(8)));
typedef _Float16 h16x8 __attribute__((ext_vector_type(8)));
typedef _Float16 h16x2 __attribute__((ext_vector_type(2)));
typedef float f32x4 __attribute__((ext_vector_type(4)));
typedef unsigned short u16x8 __attribute__((ext_vector_type(8)));

#define K1 1.4426950408889634f   /* log2(e)   */
#define K2 2.8853900817779268f   /* 2*log2(e) */

// ---- ws layout (bytes) ----
#define WS_XWK   0ull                       /* EXW f16 [2048][16][128][8] = 67,108,864 */
#define WS_FX    67108864ull                /* [2048][128] f32 */
#define WS_GX    (WS_FX + 1048576ull)
#define WS_FRAG  (WS_GX + 1048576ull)       /* 192 tiles * 64 lanes * 16B */
#define WS_PAR   (WS_FRAG + 196608ull)      /* packed params, 5392 B */

// ---- k_main LDS layout (bytes) ----
#define L_XW    0        /* EXW [4][16][128][8] f16 = 131072 */
#define L_DCA   131072   /* [8 kt][64 lane][8] bf16 = 8192 */
#define L_EPH   139264   /* [4][128] f16 = 1024 */
#define L_GT    140288   /* [512][4] f16 = 4096 */
#define L_SP    144384   /* [16 waves][4] f32 = 256 */
#define L_Y     144640   /* [4][128] f32 = 2048 */
#define L_PAR   146688   /* 5392 -> pad 5408 */
#define L_RED   152096   /* [512] f32 = 2048 */
#define L_CTX   154144   /* [4] f32 */
#define L_TOTAL 154160

__device__ __forceinline__ float fexp2(float x){
#if __has_builtin(__builtin_amdgcn_exp2f)
  return __builtin_amdgcn_exp2f(x);
#else
  return exp2f(x);
#endif
}
__device__ __forceinline__ float frcp(float x){
#if __has_builtin(__builtin_amdgcn_rcpf)
  return __builtin_amdgcn_rcpf(x);
#else
  return 1.0f / x;
#endif
}
__device__ __forceinline__ _Float16 hrcp(_Float16 x){
#if __has_builtin(__builtin_amdgcn_rcph)
  return __builtin_amdgcn_rcph(x);
#else
  return (_Float16)frcp((float)x);
#endif
}
#if __has_builtin(__builtin_amdgcn_fdot2)
#define FDOT2(a,b,c) __builtin_amdgcn_fdot2((a),(b),(c),false)
#else
#define FDOT2(a,b,c) fmaf((float)(a)[0],(float)(b)[0], fmaf((float)(a)[1],(float)(b)[1],(c)))
#endif
__device__ __forceinline__ unsigned short f2bf(float f){
  unsigned u = __builtin_bit_cast(unsigned, f);
  u = (u + 0x7FFFu + ((u >> 16) & 1u)) >> 16;
  return (unsigned short)u;
}
__device__ __forceinline__ unsigned short f2h(float f){
  _Float16 h = (_Float16)f;
  return __builtin_bit_cast(unsigned short, h);
}
__device__ __forceinline__ float h2f(unsigned short u){
  return (float)__builtin_bit_cast(_Float16, u);
}
#if __has_builtin(__builtin_amdgcn_update_dpp)
template<int C>
__device__ __forceinline__ float dppadd(float v){
  int t = __builtin_amdgcn_update_dpp(0, __builtin_bit_cast(int, v), C, 0xF, 0xF, true);
  return v + __builtin_bit_cast(float, t);
}
#define HAVE_DPP 1
#else
#define HAVE_DPP 0
#endif

// ============ k1: EXW = 2^(clamp((X @ W1x^T)*K2)), f16 blocked [b][jblk][i][8] ============
__global__ __launch_bounds__(256) void k_xw(const float* __restrict__ X,
                                            const float* __restrict__ W1,
                                            unsigned short* __restrict__ xwk){
  extern __shared__ char smem[];
  unsigned short* A  = (unsigned short*)smem;            // [128][136] bf16 (i,k)
  unsigned short* Bt = (unsigned short*)(smem + 34816);  // [128][136] bf16 (j,k)
  const int tid = threadIdx.x;
  const int bg = blockIdx.x;
  const float* Xb = X + (size_t)bg * TM1 * 128;
  for (int idx = tid; idx < 8192; idx += 256){
    int i = idx >> 6, k2 = (idx & 63) * 2;
    float x0 = 0.f, x1 = 0.f;
    if (i < TM1){ float2 v = *(const float2*)(Xb + i*128 + k2); x0 = v.x; x1 = v.y; }
    ((unsigned*)A)[i*68 + (idx & 63)] = (unsigned)f2bf(x0) | ((unsigned)f2bf(x1) << 16);
  }
  for (int idx = tid; idx < 8192; idx += 256){
    int j = idx >> 6, k2 = (idx & 63) * 2;
    float2 v = *(const float2*)(W1 + j*384 + 256 + k2);
    ((unsigned*)Bt)[j*68 + (idx & 63)] = (unsigned)f2bf(v.x) | ((unsigned)f2bf(v.y) << 16);
  }
  __syncthreads();
  const int wv = tid >> 6, l = tid & 63;
  f32x4 acc[8][2];
#pragma unroll
  for (int mt = 0; mt < 8; ++mt)
#pragma unroll
    for (int nt = 0; nt < 2; ++nt) acc[mt][nt] = (f32x4){0.f,0.f,0.f,0.f};
#pragma unroll
  for (int kt = 0; kt < 4; ++kt){
    s16x8 bf0 = *(const s16x8*)(Bt + ((wv*2+0)*16 + (l&15))*136 + (l>>4)*8 + kt*32);
    s16x8 bf1 = *(const s16x8*)(Bt + ((wv*2+1)*16 + (l&15))*136 + (l>>4)*8 + kt*32);
#pragma unroll
    for (int mt = 0; mt < 8; ++mt){
      s16x8 af = *(const s16x8*)(A + (mt*16 + (l&15))*136 + (l>>4)*8 + kt*32);
      acc[mt][0] = __builtin_amdgcn_mfma_f32_16x16x32_bf16(af, bf0, acc[mt][0], 0,0,0);
      acc[mt][1] = __builtin_amdgcn_mfma_f32_16x16x32_bf16(af, bf1, acc[mt][1], 0,0,0);
    }
  }
  unsigned short* dst = xwk + (size_t)bg * 16384;
#pragma unroll
  for (int mt = 0; mt < 8; ++mt){
#pragma unroll
    for (int nt = 0; nt < 2; ++nt){
      int j = (wv*2+nt)*16 + (l & 15);
      int jblk = j >> 3, jr = j & 7;
#pragma unroll
      for (int r = 0; r < 4; ++r){
        int i = mt*16 + (l>>4)*4 + r;
        float ux = fminf(fmaxf(acc[mt][nt][r] * K2, -15.f), 15.f);
        dst[(jblk*128 + i)*8 + jr] = f2h(fexp2(ux));
      }
    }
  }
}

// ============ k1b: FX = X @ fcW[0:128], GX = X @ fcfW[128:256]  (f32 accurate) ============
__global__ __launch_bounds__(128) void k_fxgx(const float* __restrict__ X,
                                              const float* __restrict__ fcW,
                                              const float* __restrict__ fcfW,
                                              float* __restrict__ FX,
                                              float* __restrict__ GX){
  const int bg = blockIdx.x;
  const int l = threadIdx.x & 63, wv = threadIdx.x >> 6;
  float fw0 = fcW[l], fw1 = fcW[64 + l];
  float gw0 = fcfW[128 + l], gw1 = fcfW[192 + l];
  const float* Xb = X + (size_t)bg * TM1 * 128;
  for (int i = wv; i < TM1; i += 2){
    float x0 = Xb[i*128 + l], x1 = Xb[i*128 + 64 + l];
    float p = x0*fw0 + x1*fw1;
    float g = x0*gw0 + x1*gw1;
#pragma unroll
    for (int m = 1; m < 64; m <<= 1){ p += __shfl_xor(p, m, 64); g += __shfl_xor(g, m, 64); }
    if (l == 0){ FX[bg*128 + i] = p; GX[bg*128 + i] = g; }
  }
  if (threadIdx.x == 0){ FX[bg*128 + 127] = 0.f; GX[bg*128 + 127] = 0.f; }
}

// ============ k2: weight B-fragment blob + params pack ============
__global__ __launch_bounds__(64) void k_pack(const float* __restrict__ W1,
                                             const float* __restrict__ Whh,
                                             const float* __restrict__ W2,
                                             const float* __restrict__ b1,
                                             const float* __restrict__ bih,
                                             const float* __restrict__ bhh,
                                             const float* __restrict__ Wih,
                                             const float* __restrict__ fcW,
                                             const float* __restrict__ fcb,
                                             const float* __restrict__ fcfW,
                                             const float* __restrict__ fcfb,
                                             char* __restrict__ ws){
  const int tile = blockIdx.x, l = threadIdx.x;
  s16x8 v;
  if (tile < 64){
    int nt = tile >> 3, ct = tile & 7;
    int row = nt*16 + (l & 15);
    int kb = ct*32 + (l >> 4)*8;
#pragma unroll
    for (int r = 0; r < 8; ++r) v[r] = (short)f2bf(W1[row*384 + kb + r]);
  } else {
    int g = tile - 64; int nt = g >> 2, kt = g & 3;
    int row = nt*16 + (l & 15);
    int kb = kt*32 + (l >> 4)*8;
#pragma unroll
    for (int r = 0; r < 8; ++r) v[r] = (short)f2bf(Whh[row*128 + kb + r]);
  }
  *(s16x8*)(ws + WS_FRAG + ((size_t)tile*64 + l)*16) = v;
  if (tile == 0){
    char* par = ws + WS_PAR;
    for (int j = l; j < 128; j += 64){
      ((unsigned short*)par)[j] = f2h(-2.f * W2[j]);   // w2h f16
      ((float*)(par + 256))[j] = b1[j] * K2;           // b1K
      ((float*)(par + 4864))[j] = fcfW[j];             // fcf_d
    }
    for (int n = l; n < 512; n += 64){
      ((float*)(par + 768))[n] = bih[n] + bhh[n];      // biassum
      ((float*)(par + 2816))[n] = Wih[n];              // W_ih
    }
    if (l == 0){
      ((float*)(par + 5376))[0] = fcW[128];            // y coeff
      ((float*)(par + 5376))[1] = fcb[0];
      ((float*)(par + 5376))[2] = fcfb[0];
      ((float*)(par + 5376))[3] = 0.f;
    }
  }
}

// ============ k3: persistent recurrence, 4 batches / block ============
__global__ __launch_bounds__(1024, 4) void k_main(const char* __restrict__ ws,
                                                  const float* __restrict__ dn,
                                                  const float* __restrict__ cn,
                                                  const float* __restrict__ yprev,
                                                  float* __restrict__ out){
  extern __shared__ char smem[];
  const int tid = threadIdx.x;
  const int wv = tid >> 6, l = tid & 63;
  const int bg0 = blockIdx.x * 4;
  const bool wlt8 = (wv < 8);

  // ---- P0: stage EXW tile, yprev, params; zero dcA ----
  {
    const u16x8* src = (const u16x8*)(ws + (size_t)bg0 * 32768);
    u16x8* dstv = (u16x8*)(smem + L_XW);
    for (int c = tid; c < 8192; c += 1024) dstv[c] = src[c];
    const f32x4* ps = (const f32x4*)(ws + WS_PAR);
    f32x4* pd = (f32x4*)(smem + L_PAR);
    for (int c = tid; c < 337; c += 1024) pd[c] = ps[c];
    float* yd = (float*)(smem + L_Y);
    if (tid < 512){
      int b = tid >> 7, tt = tid & 127;
      yd[tid] = (tt < TM1) ? yprev[(size_t)(bg0 + b)*TM1 + tt] : 0.f;
    }
    unsigned* z = (unsigned*)(smem + L_DCA);
    for (int c = tid; c < 2048; c += 1024) z[c] = 0u;
  }

  // weight fragments (persistent in VGPRs/AGPRs): 3 groups x 4 k-tiles per wave
  size_t t0, t1, t2;
  if (wlt8){ t0 = (size_t)wv * 8192; t1 = t0 + 4096; t2 = 65536 + (size_t)wv * 4096; }
  else { int m = wv - 8; t0 = 65536 + (size_t)(8 + m*3) * 4096; t1 = t0 + 4096; t2 = t1 + 4096; }
  const char* blob = ws + WS_FRAG;
#define LB(o) (*(const s16x8*)(blob + (o) + (size_t)l*16))
  s16x8 w00=LB(t0), w01=LB(t0+1024), w02=LB(t0+2048), w03=LB(t0+3072);
  s16x8 w10=LB(t1), w11=LB(t1+1024), w12=LB(t1+2048), w13=LB(t1+3072);
  s16x8 w20=LB(t2), w21=LB(t2+1024), w22=LB(t2+2048), w23=LB(t2+3072);
#undef LB

  // P4 mapping (pb in low bits -> conflict-free gt16/dcA access)
  const int pb = tid & 3, pj = (tid >> 2) & 127;
  float d_reg = 0.f, c_reg = 0.f;
  if (tid < 512){ d_reg = dn[(bg0+pb)*128 + pj]; c_reg = cn[(bg0+pb)*128 + pj]; }

  // P2 mapping: wave -> (batch, row block); lane -> (half, row)
  const int b2 = wv >> 2, r0 = (wv & 3) * 32, hf = l >> 5, i2 = r0 + (l & 31);
  const float fxr = ((const float*)(ws + WS_FX))[(bg0 + b2)*128 + i2];
  const float gxr = ((const float*)(ws + WS_GX))[(bg0 + b2)*128 + i2];
  const float maskf = (i2 < TM1) ? 1.f : 0.f;

  __syncthreads();
  unsigned short* dcA = (unsigned short*)(smem + L_DCA);
  const int wr_d = ((pj >> 5)      * 64 + ((pj >> 3) & 3) * 16 + pb) * 8 + (pj & 7);
  const int wr_c = (((pj >> 5) + 4) * 64 + ((pj >> 3) & 3) * 16 + pb) * 8 + (pj & 7);
  if (tid < 512){ dcA[wr_d] = f2bf(d_reg); dcA[wr_c] = f2bf(c_reg); }

  unsigned short* eph = (unsigned short*)(smem + L_EPH);
  unsigned short* gt16 = (unsigned short*)(smem + L_GT);
  float* red = (float*)(smem + L_RED);
  float* ctxL = (float*)(smem + L_CTX);
  const float* yL = (const float*)(smem + L_Y);
  const float* b1K  = (const float*)(smem + L_PAR + 256);
  const float* bsum = (const float*)(smem + L_PAR + 768);
  const float* wih  = (const float*)(smem + L_PAR + 2816);
  const float* fcfd = (const float*)(smem + L_PAR + 4864);
  const float* scal = (const float*)(smem + L_PAR + 5376);

  // hoist per-thread constants
  float wih0 = wih[pj], wih1 = wih[128+pj], wih2 = wih[256+pj], wih3 = wih[384+pj];
  float bs0 = bsum[pj], bs1 = bsum[128+pj], bs2 = bsum[256+pj], bs3 = bsum[384+pj];
  float sc0 = scal[0], sc1 = scal[1];
  __syncthreads();

  const int abyte = l * 16;
  const int cb = wlt8 ? 1 : 0;
  float ctxg = 0.f;

  // P2 loop-invariant bases (ushort units)
  const unsigned short* xwb = (const unsigned short*)(smem + L_XW)
                              + ((b2*16 + hf*8)*128 + i2)*8;
  const unsigned short* epb0 = eph + b2*128 + hf*64;
  const unsigned short* w2b = (const unsigned short*)(smem + L_PAR) + hf*64;

  for (int t = 0; t < TM1; ++t){
    // ---- P1: MFMA pre (K=256 over [d;c]) + gates_hh (K=128 over d); EP = 2^pre ----
    {
      f32x4 z = (f32x4){0.f,0.f,0.f,0.f};
      f32x4 ac0 = z, ac1 = z, ac2 = z;
      s16x8 a0, a1, a2, a3, b0, b1, b2r, b3;
      a0 = *(const s16x8*)((char*)dcA + 0*1024 + abyte);
      a1 = *(const s16x8*)((char*)dcA + 1*1024 + abyte);
      a2 = *(const s16x8*)((char*)dcA + 2*1024 + abyte);
      a3 = *(const s16x8*)((char*)dcA + 3*1024 + abyte);
      if (cb){
        b0 = *(const s16x8*)((char*)dcA + 4*1024 + abyte);
        b1 = *(const s16x8*)((char*)dcA + 5*1024 + abyte);
        b2r = *(const s16x8*)((char*)dcA + 6*1024 + abyte);
        b3 = *(const s16x8*)((char*)dcA + 7*1024 + abyte);
      } else { b0 = a0; b1 = a1; b2r = a2; b3 = a3; }
      ac0 = __builtin_amdgcn_mfma_f32_16x16x32_bf16(a0, w00, ac0, 0,0,0);
      ac0 = __builtin_amdgcn_mfma_f32_16x16x32_bf16(a1, w01, ac0, 0,0,0);
      ac0 = __builtin_amdgcn_mfma_f32_16x16x32_bf16(a2, w02, ac0, 0,0,0);
      ac0 = __builtin_amdgcn_mfma_f32_16x16x32_bf16(a3, w03, ac0, 0,0,0);
      ac2 = __builtin_amdgcn_mfma_f32_16x16x32_bf16(a0, w20, ac2, 0,0,0);
      ac2 = __builtin_amdgcn_mfma_f32_16x16x32_bf16(a1, w21, ac2, 0,0,0);
      ac2 = __builtin_amdgcn_mfma_f32_16x16x32_bf16(a2, w22, ac2, 0,0,0);
      ac2 = __builtin_amdgcn_mfma_f32_16x16x32_bf16(a3, w23, ac2, 0,0,0);
      ac1 = __builtin_amdgcn_mfma_f32_16x16x32_bf16(b0, w10, ac1, 0,0,0);
      ac1 = __builtin_amdgcn_mfma_f32_16x16x32_bf16(b1, w11, ac1, 0,0,0);
      ac1 = __builtin_amdgcn_mfma_f32_16x16x32_bf16(b2r, w12, ac1, 0,0,0);
      ac1 = __builtin_amdgcn_mfma_f32_16x16x32_bf16(b3, w13, ac1, 0,0,0);
      if (l < 16){
        if (wlt8){
          int j = wv*16 + l;
          float bb = b1K[j];
          float u0 = fminf(fmaxf((ac0[0] + ac1[0])*K2 + bb, -15.f), 15.f);
          float u1 = fminf(fmaxf((ac0[1] + ac1[1])*K2 + bb, -15.f), 15.f);
          float u2 = fminf(fmaxf((ac0[2] + ac1[2])*K2 + bb, -15.f), 15.f);
          float u3 = fminf(fmaxf((ac0[3] + ac1[3])*K2 + bb, -15.f), 15.f);
          eph[0*128 + j] = f2h(fexp2(u0));
          eph[1*128 + j] = f2h(fexp2(u1));
          eph[2*128 + j] = f2h(fexp2(u2));
          eph[3*128 + j] = f2h(fexp2(u3));
          unsigned lo = (unsigned)f2h(ac2[0]) | ((unsigned)f2h(ac2[1]) << 16);
          unsigned hi = (unsigned)f2h(ac2[2]) | ((unsigned)f2h(ac2[3]) << 16);
          *(uint2*)((char*)gt16 + j*8) = make_uint2(lo, hi);
        } else {
          int nb = (8 + (wv - 8)*3)*16 + l;
          unsigned lo, hi;
          lo = (unsigned)f2h(ac0[0]) | ((unsigned)f2h(ac0[1]) << 16);
          hi = (unsigned)f2h(ac0[2]) | ((unsigned)f2h(ac0[3]) << 16);
          *(uint2*)((char*)gt16 + nb*8) = make_uint2(lo, hi);
          lo = (unsigned)f2h(ac1[0]) | ((unsigned)f2h(ac1[1]) << 16);
          hi = (unsigned)f2h(ac1[2]) | ((unsigned)f2h(ac1[3]) << 16);
          *(uint2*)((char*)gt16 + (nb+16)*8) = make_uint2(lo, hi);
          lo = (unsigned)f2h(ac2[0]) | ((unsigned)f2h(ac2[1]) << 16);
          hi = (unsigned)f2h(ac2[2]) | ((unsigned)f2h(ac2[3]) << 16);
          *(uint2*)((char*)gt16 + (nb+32)*8) = make_uint2(lo, hi);
        }
      }
    }
    __syncthreads();   // bar A

    // ---- P2 (+fused P3): E = EXW*EP, r = hrcp(1+E), s += fdot2(r, w2) ----
    {
      float sacc = 0.f;
      h16x8 ew = *(const h16x8*)(xwb);
      h16x8 ep = *(const h16x8*)(epb0);
      h16x8 w2 = *(const h16x8*)(w2b);
#pragma unroll
      for (int jb = 0; jb < 8; ++jb){
        h16x8 ewn, epn, w2n;
        if (jb < 7){
          ewn = *(const h16x8*)(xwb + (jb+1)*1024);
          epn = *(const h16x8*)(epb0 + (jb+1)*8);
          w2n = *(const h16x8*)(w2b + (jb+1)*8);
        }
        h16x8 E = ew * ep;
        h16x8 D = E + (_Float16)1.0f;
        h16x2 r0 = { hrcp(D[0]), hrcp(D[1]) };
        h16x2 r1 = { hrcp(D[2]), hrcp(D[3]) };
        h16x2 r2 = { hrcp(D[4]), hrcp(D[5]) };
        h16x2 r3 = { hrcp(D[6]), hrcp(D[7]) };
        h16x2 wv0 = { w2[0], w2[1] }, wv1 = { w2[2], w2[3] };
        h16x2 wv2 = { w2[4], w2[5] }, wv3 = { w2[6], w2[7] };
        sacc = FDOT2(r0, wv0, sacc);
        sacc = FDOT2(r1, wv1, sacc);
        sacc = FDOT2(r2, wv2, sacc);
        sacc = FDOT2(r3, wv3, sacc);
        if (jb < 7){ ew = ewn; ep = epn; w2 = w2n; }
      }
      float sfull = sacc + __shfl_xor(sacc, 32, 64);
      float ee = fexp2(sfull * K1) * maskf;
      float aa = ee * fxr;
      float gg = ee * gxr;
#if HAVE_DPP
      ee = dppadd<0xB1>(ee);  aa = dppadd<0xB1>(aa);  gg = dppadd<0xB1>(gg);
      ee = dppadd<0x4E>(ee);  aa = dppadd<0x4E>(aa);  gg = dppadd<0x4E>(gg);
      ee = dppadd<0x124>(ee); aa = dppadd<0x124>(aa); gg = dppadd<0x124>(gg);
      ee = dppadd<0x128>(ee); aa = dppadd<0x128>(aa); gg = dppadd<0x128>(gg);
      // row_bcast15: lanes 16-31 accumulate row0's sum -> full 32-lane total
      ee = dppadd<0x142>(ee); aa = dppadd<0x142>(aa); gg = dppadd<0x142>(gg);
      if (l == 16) *(f32x4*)(smem + L_SP + wv*16) = (f32x4){ee, aa, gg, 0.f};
#else
#pragma unroll
      for (int m = 1; m < 32; m <<= 1){
        ee += __shfl_xor(ee, m, 64);
        aa += __shfl_xor(aa, m, 64);
        gg += __shfl_xor(gg, m, 64);
      }
      if (l == 0) *(f32x4*)(smem + L_SP + wv*16) = (f32x4){ee, aa, gg, 0.f};
#endif
    }
    __syncthreads();   // bar B

    // ---- P4: finalize softmax sums + LSTM pointwise ----
    if (tid < 512){
      const f32x4* sp = (const f32x4*)(smem + L_SP) + pb*4;
      f32x4 p0 = sp[0], p1 = sp[1], p2 = sp[2], p3 = sp[3];
      float E = (p0[0]+p1[0]) + (p2[0]+p3[0]);
      float A = (p0[1]+p1[1]) + (p2[1]+p3[1]);
      float G = (p0[2]+p1[2]) + (p2[2]+p3[2]);
      float rE = frcp(E);
      float yt = yL[pb*128 + t];
      float ymv = A*rE + sc0*yt + sc1;
      ctxg = G*rE;
      float xi = h2f(gt16[tid       ]) + wih0*ymv + bs0;
      float xf = h2f(gt16[512  + tid]) + wih1*ymv + bs1;
      float xg = h2f(gt16[1024 + tid]) + wih2*ymv + bs2;
      float xo = h2f(gt16[1536 + tid]) + wih3*ymv + bs3;
      float si = frcp(1.f + fexp2(-xi*K1));
      float sf = frcp(1.f + fexp2(-xf*K1));
      float so = frcp(1.f + fexp2(-xo*K1));
      float tg = 1.f - 2.f*frcp(1.f + fexp2(xg*K2));
      c_reg = sf*c_reg + si*tg;
      float tc = 1.f - 2.f*frcp(1.f + fexp2(c_reg*K2));
      d_reg = so*tc;
      dcA[wr_d] = f2bf(d_reg);
      dcA[wr_c] = f2bf(c_reg);
    }
    __syncthreads();   // bar C
  }

  // ---- epilogue: outputs ----
  if (tid < 512){
    out[2048 + (bg0 + pb)*128 + pj] = d_reg;
    out[2048 + 262144 + (bg0 + pb)*128 + pj] = c_reg;
    red[pb*128 + pj] = fcfd[pj] * d_reg;
    if (pj == 0) ctxL[pb] = ctxg;
  }
  __syncthreads();
  if (wv < 4){
    float v = red[wv*128 + l] + red[wv*128 + 64 + l];
#pragma unroll
    for (int m = 1; m < 64; m <<= 1) v += __shfl_xor(v, m, 64);
    if (l == 0) out[bg0 + wv] = v + ctxL[wv] + ((const float*)(smem + L_PAR + 5376))[2];
  }
}

extern "C" void kernel_launch(void* const* d_in, const int* in_sizes, int n_in,
                              void* d_out, int out_size, void* d_ws, size_t ws_size,
                              hipStream_t stream){
  const float* X     = (const float*)d_in[0];
  const float* yprev = (const float*)d_in[1];
  const float* dn    = (const float*)d_in[2];
  const float* cn    = (const float*)d_in[3];
  const float* W1    = (const float*)d_in[4];
  const float* b1    = (const float*)d_in[5];
  const float* W2    = (const float*)d_in[6];
  /* d_in[7] = attn_b2: softmax-shift-invariant, unused */
  const float* Wih   = (const float*)d_in[8];
  const float* Whh   = (const float*)d_in[9];
  const float* bih   = (const float*)d_in[10];
  const float* bhh   = (const float*)d_in[11];
  const float* fcW   = (const float*)d_in[12];
  const float* fcb   = (const float*)d_in[13];
  const float* fcfW  = (const float*)d_in[14];
  const float* fcfb  = (const float*)d_in[15];
  char* ws = (char*)d_ws;
  float* out = (float*)d_out;
  (void)in_sizes; (void)n_in; (void)out_size; (void)ws_size;

  hipFuncSetAttribute(reinterpret_cast<const void*>(k_xw),
                      hipFuncAttributeMaxDynamicSharedMemorySize, 69632);
  hipFuncSetAttribute(reinterpret_cast<const void*>(k_main),
                      hipFuncAttributeMaxDynamicSharedMemorySize, L_TOTAL);

  k_xw<<<2048, 256, 69632, stream>>>(X, W1, (unsigned short*)ws);
  k_fxgx<<<2048, 128, 0, stream>>>(X, fcW, fcfW,
                                   (float*)(ws + WS_FX), (float*)(ws + WS_GX));
  k_pack<<<192, 64, 0, stream>>>(W1, Whh, W2, b1, bih, bhh, Wih,
                                 fcW, fcb, fcfW, fcfb, ws);
  k_main<<<512, 1024, L_TOTAL, stream>>>(ws, dn, cn, yprev, out);
}